// Round 9
// baseline (396.866 us; speedup 1.0000x reference)
//
#include <hip/hip_runtime.h>
#include <hip/hip_bf16.h>

#define BB 16
#define SS 1024
#define DD 768
#define HH 12
#define DH 64

typedef short short8 __attribute__((ext_vector_type(8)));
typedef float f32x4 __attribute__((ext_vector_type(4)));
typedef float f32x16 __attribute__((ext_vector_type(16)));
typedef unsigned int uv2 __attribute__((ext_vector_type(2)));

__device__ inline float b2f(unsigned short v) {
    union { unsigned int u; float f; } x; x.u = ((unsigned int)v) << 16; return x.f;
}
__device__ inline unsigned short f2b(float f) {
    unsigned int u = __float_as_uint(f);
    u += 0x7FFFu + ((u >> 16) & 1u);   // round-to-nearest-even
    return (unsigned short)(u >> 16);
}
// packed fp32x2 -> bf16x2 (v_cvt_pk_bf16_f32 on gfx950)
__device__ inline unsigned int pk2(float a, float b) {
    __hip_bfloat162 h = __float22bfloat162_rn(make_float2(a, b));
    return *(unsigned int*)&h;
}
// raw v_exp_f32 (args are > -126 here; ocml's denormal guard is dead weight)
__device__ __forceinline__ float fast_exp2(float x) {
#if __has_builtin(__builtin_amdgcn_exp2f)
    return __builtin_amdgcn_exp2f(x);
#else
    return exp2f(x);
#endif
}
__device__ inline void cvt8(unsigned short* dst, const float* src) {
    const float4 f0 = *(const float4*)src;
    const float4 f1 = *(const float4*)(src + 4);
    unsigned short t[8] = {f2b(f0.x), f2b(f0.y), f2b(f0.z), f2b(f0.w),
                           f2b(f1.x), f2b(f1.y), f2b(f1.z), f2b(f1.w)};
    *(uint4*)dst = *(const uint4*)t;
}
// async global->LDS, 16B per lane; lds dst wave-uniform (HW adds lane*16)
__device__ __forceinline__ void async16(const void* g, void* l) {
    __builtin_amdgcn_global_load_lds(
        (const __attribute__((address_space(1))) void*)g,
        (__attribute__((address_space(3))) void*)l, 16, 0, 0);
}

// ---------------------------------------------------------------------------
// Kernel 0: input-dtype probe (flag: 1 = fp32 inputs, 0 = bf16).
// R8 lesson: folding this into prep_all (6721 blocks x 32KB rescans) cost
// +19us -- a 1-block dispatch is cheaper than redundant distributed work.
// ---------------------------------------------------------------------------
__global__ __launch_bounds__(256) void detect_kernel(const unsigned short* __restrict__ X,
                                                     int* __restrict__ flag) {
    __shared__ int s;
    if (threadIdx.x == 0) s = 0;
    __syncthreads();
    int c = 0;
    for (int i = threadIdx.x; i < 16384; i += 256) {
        unsigned short v = X[i];
        if ((v & 0x7FFFu) >= 0x7F80u) c = 1;
    }
    if (c) s = 1;
    __syncthreads();
    if (threadIdx.x == 0) flag[0] = s;
}

// ---------------------------------------------------------------------------
// Merged prep: X->bf16 (blocks 0..6143), W transpose (6144..6719), bias (6720).
// ---------------------------------------------------------------------------
__global__ __launch_bounds__(256) void prep_all(
    const void* __restrict__ Xv,
    const void* __restrict__ Wqv, const void* __restrict__ bqv,
    const void* __restrict__ Wkv, const void* __restrict__ bkv,
    const void* __restrict__ Wvv, const void* __restrict__ bvv,
    const void* __restrict__ Wov, const void* __restrict__ bov,
    const int* __restrict__ flag,
    unsigned short* __restrict__ Xb, unsigned short* __restrict__ Wc,
    unsigned short* __restrict__ Wot, unsigned short* __restrict__ bc,
    float* __restrict__ bo32)
{
    __shared__ unsigned short Ls[64][72];
    const int dt = *flag;
    const int u = threadIdx.x;
    const int bx = blockIdx.x;

    if (bx < 6144) {                       // ---- X convert
        size_t base = ((size_t)bx * 256 + u) * 8;
        if (dt) cvt8(Xb + base, (const float*)Xv + base);
        else    *(uint4*)(Xb + base) = *(const uint4*)((const unsigned short*)Xv + base);
        return;
    }
    if (bx < 6720) {                       // ---- weight transpose to [n][k]
        const int idx = bx - 6144;
        const int kt = idx % 12;
        const int y  = idx / 12;           // 0..47
        const int rk = u >> 2;
        const int e0 = (u & 3) * 16;

        const void* src; size_t srcBase;
        unsigned short* dst; int drow;
        if (y < 36) {
            int z = y / 12, h = y % 12;
            src = (z == 0) ? Wqv : (z == 1) ? Wkv : Wvv;
            srcBase = ((size_t)h * DD + kt * 64 + rk) * DH;
            dst = Wc; drow = z * 768 + h * 64;
        } else {
            int nt = y - 36;
            src = Wov;
            srcBase = (size_t)(kt * 64 + rk) * DD + nt * 64;
            dst = Wot; drow = nt * 64;
        }
#pragma unroll
        for (int ii = 0; ii < 2; ++ii) {
            int e = e0 + ii * 8;
            if (dt) {
                const float* p = (const float*)src + srcBase + e;
                float4 a = *(const float4*)p, b = *(const float4*)(p + 4);
                float v[8] = {a.x, a.y, a.z, a.w, b.x, b.y, b.z, b.w};
#pragma unroll
                for (int j = 0; j < 8; ++j) Ls[e + j][rk] = f2b(v[j]);
            } else {
                union { uint4 v; unsigned short s[8]; } t;
                t.v = *(const uint4*)((const unsigned short*)src + srcBase + e);
#pragma unroll
                for (int j = 0; j < 8; ++j) Ls[e + j][rk] = t.s[j];
            }
        }
        __syncthreads();
        const int e = u >> 2, q = u & 3;
#pragma unroll
        for (int ii = 0; ii < 2; ++ii) {
            int kk = q * 16 + ii * 8;
            *(uint4*)(dst + (size_t)(drow + e) * DD + kt * 64 + kk) = *(const uint4*)(&Ls[e][kk]);
        }
        return;
    }
    // ---- biases
    for (int n = u; n < 2304; n += 256) {
        int z = n / 768, i = n % 768;
        const void* b = (z == 0) ? bqv : (z == 1) ? bkv : bvv;
        bc[n] = dt ? f2b(((const float*)b)[i]) : ((const unsigned short*)b)[i];
    }
    for (int n = u; n < 768; n += 256)
        bo32[n] = dt ? ((const float*)bov)[n] : b2f(((const unsigned short*)bov)[n]);
}

// ---------------------------------------------------------------------------
// Kernel 1: merged QKV GEMM, 128x128 tiles, XOR-swizzled LDS. grid (18, 128).
// 2-phase dbuf pipeline + bijective XCD swizzle (measured: 79.5 -> 75.0 us,
// FETCH 122 -> 83.5 MB). LDS 64KB (2 blocks/CU).
// Q is pre-scaled by Csc = 0.125*log2(e) so attn's softmax needs no multiply.
// ---------------------------------------------------------------------------
__global__ __launch_bounds__(256) void qkv_gemm(
    const unsigned short* __restrict__ Xb,
    const unsigned short* __restrict__ Wc,
    const unsigned short* __restrict__ bc,
    unsigned short* __restrict__ Qb, unsigned short* __restrict__ Kb,
    unsigned short* __restrict__ Vtb)
{
    __shared__ __align__(16) unsigned short lds[32768];  // 64KB: 2 x (A 8192 | B 8192)

    const int u = threadIdx.x;
    const int lane = u & 63, w = u >> 6;
    const int ln = lane & 15, quad = lane >> 4;
    const int wm = w & 1, wn = w >> 1;

    // XCD swizzle (bijective: 2304 = 8*288)
    const int flat = blockIdx.y * 18 + blockIdx.x;
    const int sf   = (flat & 7) * 288 + (flat >> 3);
    const int nt0  = sf % 18;
    const int m0   = (sf / 18) << 7;
    const int n0   = nt0 << 7;
    const int z    = nt0 / 6;
    const int hpair = (nt0 % 6) * 2;

    const int rA = w * 32 + (lane >> 3);
    const int c8 = (((lane & 7) ^ (lane >> 3)) * 8);

    f32x4 acc[4][4];
#pragma unroll
    for (int i = 0; i < 4; ++i)
#pragma unroll
        for (int j = 0; j < 4; ++j) acc[i][j] = (f32x4){0.f, 0.f, 0.f, 0.f};

    const unsigned short* Ag = Xb + (size_t)(m0 + rA) * DD + c8;
    const unsigned short* Bg = Wc + (size_t)(n0 + rA) * DD + c8;

    // prologue: stage K-tile 0 into buffer 0
    {
        unsigned short* lA = lds + w * 2048;
        unsigned short* lB = lds + 8192 + w * 2048;
#pragma unroll
        for (int j = 0; j < 4; ++j) {
            async16(Ag + (size_t)j * 8 * DD, lA + j * 512);
            async16(Bg + (size_t)j * 8 * DD, lB + j * 512);
        }
    }
    __syncthreads();   // tile 0 resident (implicit vmcnt(0))

    for (int kb = 0; kb < 12; ++kb) {
        const int cur = kb & 1;
        // prefetch next K-tile into the other buffer (drained by end barrier)
        if (kb < 11) {
            unsigned short* lA = lds + (cur ^ 1) * 16384 + w * 2048;
            unsigned short* lB = lds + (cur ^ 1) * 16384 + 8192 + w * 2048;
            const int k0 = (kb + 1) * 64;
#pragma unroll
            for (int j = 0; j < 4; ++j) {
                async16(Ag + (size_t)j * 8 * DD + k0, lA + j * 512);
                async16(Bg + (size_t)j * 8 * DD + k0, lB + j * 512);
            }
        }
        const unsigned short* As = lds + cur * 16384;
        const unsigned short* Bs = As + 8192;
#pragma unroll
        for (int kh = 0; kh < 2; ++kh) {
            const int sx = ((kh * 4 + quad) ^ (ln & 7)) * 8;
            short8 af[4], bf[4];
#pragma unroll
            for (int t = 0; t < 4; ++t) {
                af[t] = *(const short8*)(As + (wm * 64 + t * 16 + ln) * 64 + sx);
                bf[t] = *(const short8*)(Bs + (wn * 64 + t * 16 + ln) * 64 + sx);
            }
#pragma unroll
            for (int mt = 0; mt < 4; ++mt)
#pragma unroll
                for (int nt = 0; nt < 4; ++nt)
                    acc[mt][nt] = __builtin_amdgcn_mfma_f32_16x16x32_bf16(af[mt], bf[nt], acc[mt][nt], 0, 0, 0);
        }
        __syncthreads();   // drains prefetch + guards buffer overwrite
    }

    float bias[4];
#pragma unroll
    for (int nt = 0; nt < 4; ++nt) bias[nt] = b2f(bc[n0 + wn * 64 + nt * 16 + ln]);

    const int b = m0 >> 10;
    if (z < 2) {
        unsigned short* O = (z == 0) ? Qb : Kb;
        const float sc = (z == 0) ? 0.180336880111120f : 1.0f;   // 0.125*log2(e)
        const int h = hpair + wn;
        const int sb = (m0 & 1023) + wm * 64;
#pragma unroll
        for (int mt = 0; mt < 4; ++mt)
#pragma unroll
            for (int r = 0; r < 4; ++r) {
                int s = sb + mt * 16 + quad * 4 + r;
                size_t rowo = ((size_t)(b * HH + h) * SS + s) * DH;
#pragma unroll
                for (int nt = 0; nt < 4; ++nt)
                    O[rowo + nt * 16 + ln] = f2b((acc[mt][nt][r] + bias[nt]) * sc);
            }
    } else {
        __syncthreads();
#pragma unroll
        for (int mt = 0; mt < 4; ++mt)
#pragma unroll
            for (int nt = 0; nt < 4; ++nt)
#pragma unroll
                for (int r = 0; r < 4; ++r)
                    lds[(wn * 64 + nt * 16 + ln) * 136 + wm * 64 + mt * 16 + quad * 4 + r] =
                        f2b(acc[mt][nt][r] + bias[nt]);
        __syncthreads();
        const int cc = u >> 1, half = u & 1;
        const int h = hpair + (cc >> 6), e = cc & 63;
        const int sb = (m0 & 1023) + half * 64;
        unsigned short* dst = Vtb + ((size_t)(b * HH + h) * DH + e) * SS + sb;
        const unsigned short* srcp = lds + cc * 136 + half * 64;
#pragma unroll
        for (int i = 0; i < 8; ++i)
            *(uint4*)(dst + i * 8) = *(const uint4*)(srcp + i * 8);
    }
}

// ---------------------------------------------------------------------------
// Kernel 2: flash attention, 32x32x16 MFMA core, in-register P (R6 structure,
// measured 73.7us at 4 blocks/CU). Round-9 change: __launch_bounds__(256, 5)
// -- 5 x 32KB = 160KB = exact LDS pool fit, VGPR 64 << 102 cap. +25% resident
// waves to cross-hide the serial QK->exp->pack->PV chain (kernel is
// latency-bound: MfmaUtil 38 / VALU 49 / LDS ~55, nothing saturated).
// If the driver reserves LDS and 5 don't fit, we silently stay at 4 (neutral).
// grid (8, 192).
// ---------------------------------------------------------------------------
__global__ __launch_bounds__(256, 5) void attn_kernel(
    const unsigned short* __restrict__ Kb,
    const unsigned short* __restrict__ Vtb,
    unsigned short* __restrict__ Qb)
{
    __shared__ __align__(16) unsigned short Ks[2][4096];   // dbuf [64 t][64 e] swz; also Q stage / O^T epilogue
    __shared__ __align__(16) unsigned short Vs[2][4096];   // dbuf [64 e][64 t] swz
    unsigned short* KsF = &Ks[0][0];                       // 16 KB flat view

    const int u = threadIdx.x;
    // XCD swizzle (bijective: 1536 % 8 == 0): flat -> (head, qtile)
    const int flat = (blockIdx.y << 3) | blockIdx.x;       // 0..1535, xcd = flat&7
    const int swz  = (flat & 7) * 192 + (flat >> 3);
    const int s0 = (swz & 7) << 7;
    const int bh = swz >> 3;

    const int lane = u & 63, w = u >> 6;
    const int l31 = lane & 31, hi = lane >> 5;
    const int r7 = l31 & 7;

    unsigned short* Qg = Qb + ((size_t)bh * SS + s0) * DH;
    const unsigned short* Kg = Kb + (size_t)bh * SS * DH;
    const unsigned short* Vg = Vtb + (size_t)bh * DH * SS;

    const int srow = lane >> 3;
    const int cg8  = ((lane & 7) ^ srow) * 8;

    // staging pointers (K rows t, V rows e; 16B/lane async16)
    const unsigned short* kp0 = Kg + (size_t)((w * 2 + 0) * 8 + srow) * DH + cg8;
    const unsigned short* kp1 = Kg + (size_t)((w * 2 + 1) * 8 + srow) * DH + cg8;
    const unsigned short* vp0 = Vg + (size_t)((w * 2 + 0) * 8 + srow) * SS + cg8;
    const unsigned short* vp1 = Vg + (size_t)((w * 2 + 1) * 8 + srow) * SS + cg8;

    // ---- stage Q (16 KB) through the Ks region, consume into regs ----
#pragma unroll
    for (int j = 0; j < 4; ++j) {
        const int r0 = (w * 4 + j) * 8 + srow;
        async16(Qg + (size_t)r0 * DH + cg8, KsF + (w * 4 + j) * 512);
    }
    __syncthreads();   // Q resident (implicit vmcnt(0))

    // Q B-fragments: lane holds Q[m = w*32 + l31][e = ke*16 + hi*8 + j]
    short8 qf[4];
    {
        const unsigned short* qrow = KsF + (w * 32 + l31) * 64;
#pragma unroll
        for (int ke = 0; ke < 4; ++ke)
            qf[ke] = *(const short8*)(qrow + (((ke * 2 + hi) ^ r7) * 8));
    }
    __syncthreads();   // ALL waves consumed Q -> Ks region recyclable

    // ---- stage K/V tile 0 into buffer 0 ----
    async16(kp0, &Ks[0][(w * 2 + 0) * 512]);
    async16(kp1, &Ks[0][(w * 2 + 1) * 512]);
    async16(vp0, &Vs[0][(w * 2 + 0) * 512]);
    async16(vp1, &Vs[0][(w * 2 + 1) * 512]);
    kp0 += 64 * DH; kp1 += 64 * DH; vp0 += 64; vp1 += 64;
    __syncthreads();   // tile0 resident

    short8 ones;
#pragma unroll
    for (int i = 0; i < 8; ++i) ones[i] = (short)0x3F80;   // bf16 1.0

    // A-fragment LDS offsets (shared by K and V tiles): row l31 (+tt*32 via +2048)
    int off[4];
#pragma unroll
    for (int x = 0; x < 4; ++x) off[x] = l31 * 64 + (((x * 2 + hi) ^ r7) * 8);

    f32x16 oA, oB, oL;
#pragma unroll
    for (int i = 0; i < 16; ++i) { oA[i] = 0.f; oB[i] = 0.f; oL[i] = 0.f; }

    for (int kt = 0; kt < 16; ++kt) {
        const int cur = kt & 1;
        // prefetch next K/V tile into the other buffer (end-of-iter barrier drains)
        if (kt < 15) {
            unsigned short* lk = &Ks[cur ^ 1][(w * 2) * 512];
            unsigned short* lv = &Vs[cur ^ 1][(w * 2) * 512];
            async16(kp0, lk);
            async16(kp1, lk + 512);
            async16(vp0, lv);
            async16(vp1, lv + 512);
            kp0 += 64 * DH; kp1 += 64 * DH; vp0 += 64; vp1 += 64;
        }
        const unsigned short* kc = Ks[cur];
        const unsigned short* vc = Vs[cur];

        // --- QK^T (swapped): sA = S^T rows t 0..31, sB = t 32..63, cols m ---
        f32x16 sA, sB;
#pragma unroll
        for (int i = 0; i < 16; ++i) { sA[i] = 0.f; sB[i] = 0.f; }
        __builtin_amdgcn_s_setprio(1);
#pragma unroll
        for (int ke = 0; ke < 4; ++ke) {
            short8 kf0 = *(const short8*)(kc + off[ke]);
            short8 kf1 = *(const short8*)(kc + off[ke] + 2048);
            sA = __builtin_amdgcn_mfma_f32_32x32x16_bf16(kf0, qf[ke], sA, 0, 0, 0);
            sB = __builtin_amdgcn_mfma_f32_32x32x16_bf16(kf1, qf[ke], sB, 0, 0, 0);
        }
        __builtin_amdgcn_s_setprio(0);

        // --- exp2 + pack to bf16 words (row-sum via oL MFMA below) ---
        // W[tt][i] covers t = tt*32 + {0,2,8,10,16,18,24,26}[i] + 4*hi + {0,1}
        unsigned int W0[8], W1[8];
#pragma unroll
        for (int i = 0; i < 8; ++i) {
            W0[i] = pk2(fast_exp2(sA[2 * i]), fast_exp2(sA[2 * i + 1]));
            W1[i] = pk2(fast_exp2(sB[2 * i]), fast_exp2(sB[2 * i + 1]));
        }

        // --- permlane32_swap -> PV B-frags; PV + row-sum MFMAs ---
        // permlane32_swap semantics (CDNA4): new_vdst[32:63] = old_src0[0:31],
        // new_src0[0:31] = old_vdst[32:63]; swap(W[0],W[2]) -> (.x = frag word
        // 0, .y = frag word 2) on BOTH halves.
        __builtin_amdgcn_s_setprio(1);
#define PV_STEP(Wt, ks) {                                                              \
        union { unsigned int wv[4]; short8 s; } pu;                                    \
        { uv2 rr = __builtin_amdgcn_permlane32_swap(Wt[4 * ((ks) & 1) + 0],            \
                                                    Wt[4 * ((ks) & 1) + 2], false, false); \
          pu.wv[0] = rr.x; pu.wv[2] = rr.y; }                                          \
        { uv2 rr = __builtin_amdgcn_permlane32_swap(Wt[4 * ((ks) & 1) + 1],            \
                                                    Wt[4 * ((ks) & 1) + 3], false, false); \
          pu.wv[1] = rr.x; pu.wv[3] = rr.y; }                                          \
        oL = __builtin_amdgcn_mfma_f32_32x32x16_bf16(ones, pu.s, oL, 0, 0, 0);         \
        short8 vf0 = *(const short8*)(vc + off[(ks)]);                                 \
        short8 vf1 = *(const short8*)(vc + off[(ks)] + 2048);                          \
        oA = __builtin_amdgcn_mfma_f32_32x32x16_bf16(vf0, pu.s, oA, 0, 0, 0);          \
        oB = __builtin_amdgcn_mfma_f32_32x32x16_bf16(vf1, pu.s, oB, 0, 0, 0); }
        PV_STEP(W0, 0)
        PV_STEP(W0, 1)
        PV_STEP(W1, 2)
        PV_STEP(W1, 3)
#undef PV_STEP
        __builtin_amdgcn_s_setprio(0);

        __syncthreads();   // drains prefetch (vmcnt 0) + guards buffer swap
    }

    // --- epilogue: normalize, transpose O^T -> O via Ks region, store ---
    // oL: every row of D holds sum_t P[m][t] for col m = l31 (A = all-ones).
    const float linv = 1.f / oL[0];

    unsigned short* Ob = KsF + w * 2048;   // wave-private 4KB: [32 m][64 e] swz
#define OSTORE(oc, et) {                                                   \
        _Pragma("unroll")                                                  \
        for (int rg = 0; rg < 4; ++rg) {                                   \
            uv2 wv;                                                        \
            wv.x = pk2(oc[rg * 4 + 0] * linv, oc[rg * 4 + 1] * linv);      \
            wv.y = pk2(oc[rg * 4 + 2] * linv, oc[rg * 4 + 3] * linv);      \
            *(uv2*)(Ob + l31 * 64 + ((((et) * 4 + rg) ^ r7) * 8) + hi * 4) = wv; \
        } }
    OSTORE(oA, 0)
    OSTORE(oB, 1)
#undef OSTORE

    const int rr2 = lane >> 1, q16 = lane & 1, rs = rr2 & 7;
    const unsigned short* orow = KsF + w * 2048 + rr2 * 64;
    unsigned short* gout = Qg + (size_t)(w * 32 + rr2) * DH;
#pragma unroll
    for (int i = 0; i < 4; ++i) {
        const int g = q16 * 4 + i;
        *(uint4*)(gout + g * 8) = *(const uint4*)(orow + ((g ^ rs) * 8));
    }
}

// ---------------------------------------------------------------------------
// Kernel 3: output projection, 128x128 tiles, swizzled. Single-buffer 32KB
// LDS (dbuf measured -15us here: occupancy halving outweighed the pipeline)
// + bijective XCD swizzle (768 = 8*96). out fp32. grid (6, 128).
// ---------------------------------------------------------------------------
__global__ __launch_bounds__(256) void oproj_gemm(
    const unsigned short* __restrict__ Ob,
    const unsigned short* __restrict__ Wot,
    const float* __restrict__ bo32,
    float* __restrict__ out)
{
    __shared__ __align__(16) unsigned short lds[128 * 128];
    unsigned short* As = lds;
    unsigned short* Bs = lds + 128 * 64;

    const int u = threadIdx.x;
    const int lane = u & 63, w = u >> 6;
    const int ln = lane & 15, quad = lane >> 4;
    const int wm = w & 1, wn = w >> 1;

    // XCD swizzle (bijective: 768 = 8*96)
    const int flat = blockIdx.y * 6 + blockIdx.x;
    const int sf   = (flat & 7) * 96 + (flat >> 3);
    const int n0   = (sf % 6) << 7;
    const int m0   = (sf / 6) << 7;
    const int b = m0 >> 10, s0t = m0 & 1023;

    const int rA = w * 32 + (lane >> 3);
    const int c8 = (((lane & 7) ^ (lane >> 3)) * 8);

    f32x4 acc[4][4];
#pragma unroll
    for (int i = 0; i < 4; ++i)
#pragma unroll
        for (int j = 0; j < 4; ++j) acc[i][j] = (f32x4){0.f, 0.f, 0.f, 0.f};

    const unsigned short* Bg = Wot + (size_t)(n0 + rA) * DD + c8;
    unsigned short* lA0 = As + w * 2048;
    unsigned short* lB0 = Bs + w * 2048;

    for (int kb = 0; kb < 12; ++kb) {
        if (kb) __syncthreads();
        const unsigned short* Ag = Ob + ((size_t)(b * HH + kb) * SS + s0t + rA) * DH + c8;
#pragma unroll
        for (int j = 0; j < 4; ++j) {
            async16(Ag + (size_t)j * 8 * DH, lA0 + j * 512);
            async16(Bg + (size_t)j * 8 * DD + kb * 64, lB0 + j * 512);
        }
        __syncthreads();
#pragma unroll
        for (int kh = 0; kh < 2; ++kh) {
            const int sx = ((kh * 4 + quad) ^ (ln & 7)) * 8;
            short8 af[4], bf[4];
#pragma unroll
            for (int t = 0; t < 4; ++t) {
                af[t] = *(const short8*)(As + (wm * 64 + t * 16 + ln) * 64 + sx);
                bf[t] = *(const short8*)(Bs + (wn * 64 + t * 16 + ln) * 64 + sx);
            }
#pragma unroll
            for (int mt = 0; mt < 4; ++mt)
#pragma unroll
                for (int nt = 0; nt < 4; ++nt)
                    acc[mt][nt] = __builtin_amdgcn_mfma_f32_16x16x32_bf16(af[mt], bf[nt], acc[mt][nt], 0, 0, 0);
        }
    }

    float bias[4];
#pragma unroll
    for (int nt = 0; nt < 4; ++nt) bias[nt] = bo32[n0 + wn * 64 + nt * 16 + ln];
#pragma unroll
    for (int mt = 0; mt < 4; ++mt)
#pragma unroll
        for (int r = 0; r < 4; ++r) {
            int m = m0 + wm * 64 + mt * 16 + quad * 4 + r;
            float* orow = out + (size_t)m * DD + n0 + wn * 64;
#pragma unroll
            for (int nt = 0; nt < 4; ++nt)
                orow[nt * 16 + ln] = acc[mt][nt][r] + bias[nt];
        }
}

extern "C" void kernel_launch(void* const* d_in, const int* in_sizes, int n_in,
                              void* d_out, int out_size, void* d_ws, size_t ws_size,
                              hipStream_t stream)
{
    const void* X  = d_in[0];
    const void* Wq = d_in[1];
    const void* bq = d_in[2];
    const void* Wk = d_in[3];
    const void* bk = d_in[4];
    const void* Wv = d_in[5];
    const void* bv = d_in[6];
    const void* Wo = d_in[7];
    const void* bo = d_in[8];
    float* out = (float*)d_out;

    const size_t NE = (size_t)BB * HH * SS * DH;   // 12,582,912
    char* p = (char*)d_ws;
    int* flag = (int*)p;                 p += 256;
    unsigned short* Qb  = (unsigned short*)p;  p += NE * 2;
    unsigned short* Kb  = (unsigned short*)p;  p += NE * 2;
    unsigned short* Vtb = (unsigned short*)p;  p += NE * 2;
    unsigned short* Xb  = (unsigned short*)p;  p += (size_t)BB * SS * DD * 2;
    unsigned short* Wc  = (unsigned short*)p;  p += (size_t)3 * DD * DD * 2;
    unsigned short* Wot = (unsigned short*)p;  p += (size_t)DD * DD * 2;
    unsigned short* bcb = (unsigned short*)p;  p += 4608;
    float* bo32 = (float*)p;                   p += 3072;

    detect_kernel<<<1, 256, 0, stream>>>((const unsigned short*)X, flag);
    prep_all<<<6721, 256, 0, stream>>>(X, Wq, bq, Wk, bk, Wv, bv, Wo, bo, flag,
                                       Xb, Wc, Wot, bcb, bo32);
    qkv_gemm<<<dim3(18, 128), 256, 0, stream>>>(Xb, Wc, bcb, Qb, Kb, Vtb);
    attn_kernel<<<dim3(8, 192), 256, 0, stream>>>(Kb, Vtb, Qb);
    oproj_gemm<<<dim3(6, 128), 256, 0, stream>>>(Qb, Wot, bo32, out);
}

// Round 10
// 285.738 us; speedup vs baseline: 1.3889x; 1.3889x over previous
//
#include <hip/hip_runtime.h>
#include <hip/hip_bf16.h>

#define BB 16
#define SS 1024
#define DD 768
#define HH 12
#define DH 64

typedef short short8 __attribute__((ext_vector_type(8)));
typedef float f32x4 __attribute__((ext_vector_type(4)));
typedef float f32x16 __attribute__((ext_vector_type(16)));
typedef unsigned int uv2 __attribute__((ext_vector_type(2)));

__device__ inline float b2f(unsigned short v) {
    union { unsigned int u; float f; } x; x.u = ((unsigned int)v) << 16; return x.f;
}
__device__ inline unsigned short f2b(float f) {
    unsigned int u = __float_as_uint(f);
    u += 0x7FFFu + ((u >> 16) & 1u);   // round-to-nearest-even
    return (unsigned short)(u >> 16);
}
// packed fp32x2 -> bf16x2 (v_cvt_pk_bf16_f32 on gfx950)
__device__ inline unsigned int pk2(float a, float b) {
    __hip_bfloat162 h = __float22bfloat162_rn(make_float2(a, b));
    return *(unsigned int*)&h;
}
// raw v_exp_f32 (args are > -126 here; ocml's denormal guard is dead weight)
__device__ __forceinline__ float fast_exp2(float x) {
#if __has_builtin(__builtin_amdgcn_exp2f)
    return __builtin_amdgcn_exp2f(x);
#else
    return exp2f(x);
#endif
}
// 8x fp32 -> bf16 via 4x v_cvt_pk_bf16_f32 (was 8x scalar f2b ~24 VALU ops;
// the X-convert phase of prep_all was VALU-bound, not memory-bound)
__device__ inline void cvt8(unsigned short* dst, const float* src) {
    const float4 f0 = *(const float4*)src;
    const float4 f1 = *(const float4*)(src + 4);
    uint4 o;
    o.x = pk2(f0.x, f0.y);
    o.y = pk2(f0.z, f0.w);
    o.z = pk2(f1.x, f1.y);
    o.w = pk2(f1.z, f1.w);
    *(uint4*)dst = o;
}
// async global->LDS, 16B per lane; lds dst wave-uniform (HW adds lane*16)
__device__ __forceinline__ void async16(const void* g, void* l) {
    __builtin_amdgcn_global_load_lds(
        (const __attribute__((address_space(1))) void*)g,
        (__attribute__((address_space(3))) void*)l, 16, 0, 0);
}

// ---------------------------------------------------------------------------
// Kernel 0: input-dtype probe (flag: 1 = fp32 inputs, 0 = bf16).
// R8 lesson: folding this into prep_all (6721 blocks x 32KB rescans) cost
// +19us -- a 1-block dispatch is cheaper than redundant distributed work.
// ---------------------------------------------------------------------------
__global__ __launch_bounds__(256) void detect_kernel(const unsigned short* __restrict__ X,
                                                     int* __restrict__ flag) {
    __shared__ int s;
    if (threadIdx.x == 0) s = 0;
    __syncthreads();
    int c = 0;
    for (int i = threadIdx.x; i < 16384; i += 256) {
        unsigned short v = X[i];
        if ((v & 0x7FFFu) >= 0x7F80u) c = 1;
    }
    if (c) s = 1;
    __syncthreads();
    if (threadIdx.x == 0) flag[0] = s;
}

// ---------------------------------------------------------------------------
// Merged prep: X->bf16 (blocks 0..6143), W transpose (6144..6719), bias (6720).
// ---------------------------------------------------------------------------
__global__ __launch_bounds__(256) void prep_all(
    const void* __restrict__ Xv,
    const void* __restrict__ Wqv, const void* __restrict__ bqv,
    const void* __restrict__ Wkv, const void* __restrict__ bkv,
    const void* __restrict__ Wvv, const void* __restrict__ bvv,
    const void* __restrict__ Wov, const void* __restrict__ bov,
    const int* __restrict__ flag,
    unsigned short* __restrict__ Xb, unsigned short* __restrict__ Wc,
    unsigned short* __restrict__ Wot, unsigned short* __restrict__ bc,
    float* __restrict__ bo32)
{
    __shared__ unsigned short Ls[64][72];
    const int dt = *flag;
    const int u = threadIdx.x;
    const int bx = blockIdx.x;

    if (bx < 6144) {                       // ---- X convert
        size_t base = ((size_t)bx * 256 + u) * 8;
        if (dt) cvt8(Xb + base, (const float*)Xv + base);
        else    *(uint4*)(Xb + base) = *(const uint4*)((const unsigned short*)Xv + base);
        return;
    }
    if (bx < 6720) {                       // ---- weight transpose to [n][k]
        const int idx = bx - 6144;
        const int kt = idx % 12;
        const int y  = idx / 12;           // 0..47
        const int rk = u >> 2;
        const int e0 = (u & 3) * 16;

        const void* src; size_t srcBase;
        unsigned short* dst; int drow;
        if (y < 36) {
            int z = y / 12, h = y % 12;
            src = (z == 0) ? Wqv : (z == 1) ? Wkv : Wvv;
            srcBase = ((size_t)h * DD + kt * 64 + rk) * DH;
            dst = Wc; drow = z * 768 + h * 64;
        } else {
            int nt = y - 36;
            src = Wov;
            srcBase = (size_t)(kt * 64 + rk) * DD + nt * 64;
            dst = Wot; drow = nt * 64;
        }
#pragma unroll
        for (int ii = 0; ii < 2; ++ii) {
            int e = e0 + ii * 8;
            if (dt) {
                const float* p = (const float*)src + srcBase + e;
                float4 a = *(const float4*)p, b = *(const float4*)(p + 4);
                float v[8] = {a.x, a.y, a.z, a.w, b.x, b.y, b.z, b.w};
#pragma unroll
                for (int j = 0; j < 8; ++j) Ls[e + j][rk] = f2b(v[j]);
            } else {
                union { uint4 v; unsigned short s[8]; } t;
                t.v = *(const uint4*)((const unsigned short*)src + srcBase + e);
#pragma unroll
                for (int j = 0; j < 8; ++j) Ls[e + j][rk] = t.s[j];
            }
        }
        __syncthreads();
        const int e = u >> 2, q = u & 3;
#pragma unroll
        for (int ii = 0; ii < 2; ++ii) {
            int kk = q * 16 + ii * 8;
            *(uint4*)(dst + (size_t)(drow + e) * DD + kt * 64 + kk) = *(const uint4*)(&Ls[e][kk]);
        }
        return;
    }
    // ---- biases
    for (int n = u; n < 2304; n += 256) {
        int z = n / 768, i = n % 768;
        const void* b = (z == 0) ? bqv : (z == 1) ? bkv : bvv;
        bc[n] = dt ? f2b(((const float*)b)[i]) : ((const unsigned short*)b)[i];
    }
    for (int n = u; n < 768; n += 256)
        bo32[n] = dt ? ((const float*)bov)[n] : b2f(((const unsigned short*)bov)[n]);
}

// ---------------------------------------------------------------------------
// Kernel 1: merged QKV GEMM, 128x128 tiles, XOR-swizzled LDS. grid (18, 128).
// 2-phase dbuf pipeline + bijective XCD swizzle (measured: 79.5 -> 75.0 us,
// FETCH 122 -> 83.5 MB). LDS 64KB (2 blocks/CU).
// Q is pre-scaled by Csc = 0.125*log2(e) so attn's softmax needs no multiply.
// ---------------------------------------------------------------------------
__global__ __launch_bounds__(256) void qkv_gemm(
    const unsigned short* __restrict__ Xb,
    const unsigned short* __restrict__ Wc,
    const unsigned short* __restrict__ bc,
    unsigned short* __restrict__ Qb, unsigned short* __restrict__ Kb,
    unsigned short* __restrict__ Vtb)
{
    __shared__ __align__(16) unsigned short lds[32768];  // 64KB: 2 x (A 8192 | B 8192)

    const int u = threadIdx.x;
    const int lane = u & 63, w = u >> 6;
    const int ln = lane & 15, quad = lane >> 4;
    const int wm = w & 1, wn = w >> 1;

    // XCD swizzle (bijective: 2304 = 8*288)
    const int flat = blockIdx.y * 18 + blockIdx.x;
    const int sf   = (flat & 7) * 288 + (flat >> 3);
    const int nt0  = sf % 18;
    const int m0   = (sf / 18) << 7;
    const int n0   = nt0 << 7;
    const int z    = nt0 / 6;
    const int hpair = (nt0 % 6) * 2;

    const int rA = w * 32 + (lane >> 3);
    const int c8 = (((lane & 7) ^ (lane >> 3)) * 8);

    f32x4 acc[4][4];
#pragma unroll
    for (int i = 0; i < 4; ++i)
#pragma unroll
        for (int j = 0; j < 4; ++j) acc[i][j] = (f32x4){0.f, 0.f, 0.f, 0.f};

    const unsigned short* Ag = Xb + (size_t)(m0 + rA) * DD + c8;
    const unsigned short* Bg = Wc + (size_t)(n0 + rA) * DD + c8;

    // prologue: stage K-tile 0 into buffer 0
    {
        unsigned short* lA = lds + w * 2048;
        unsigned short* lB = lds + 8192 + w * 2048;
#pragma unroll
        for (int j = 0; j < 4; ++j) {
            async16(Ag + (size_t)j * 8 * DD, lA + j * 512);
            async16(Bg + (size_t)j * 8 * DD, lB + j * 512);
        }
    }
    __syncthreads();   // tile 0 resident (implicit vmcnt(0))

    for (int kb = 0; kb < 12; ++kb) {
        const int cur = kb & 1;
        // prefetch next K-tile into the other buffer (drained by end barrier)
        if (kb < 11) {
            unsigned short* lA = lds + (cur ^ 1) * 16384 + w * 2048;
            unsigned short* lB = lds + (cur ^ 1) * 16384 + 8192 + w * 2048;
            const int k0 = (kb + 1) * 64;
#pragma unroll
            for (int j = 0; j < 4; ++j) {
                async16(Ag + (size_t)j * 8 * DD + k0, lA + j * 512);
                async16(Bg + (size_t)j * 8 * DD + k0, lB + j * 512);
            }
        }
        const unsigned short* As = lds + cur * 16384;
        const unsigned short* Bs = As + 8192;
#pragma unroll
        for (int kh = 0; kh < 2; ++kh) {
            const int sx = ((kh * 4 + quad) ^ (ln & 7)) * 8;
            short8 af[4], bf[4];
#pragma unroll
            for (int t = 0; t < 4; ++t) {
                af[t] = *(const short8*)(As + (wm * 64 + t * 16 + ln) * 64 + sx);
                bf[t] = *(const short8*)(Bs + (wn * 64 + t * 16 + ln) * 64 + sx);
            }
#pragma unroll
            for (int mt = 0; mt < 4; ++mt)
#pragma unroll
                for (int nt = 0; nt < 4; ++nt)
                    acc[mt][nt] = __builtin_amdgcn_mfma_f32_16x16x32_bf16(af[mt], bf[nt], acc[mt][nt], 0, 0, 0);
        }
        __syncthreads();   // drains prefetch + guards buffer overwrite
    }

    float bias[4];
#pragma unroll
    for (int nt = 0; nt < 4; ++nt) bias[nt] = b2f(bc[n0 + wn * 64 + nt * 16 + ln]);

    const int b = m0 >> 10;
    if (z < 2) {
        unsigned short* O = (z == 0) ? Qb : Kb;
        const float sc = (z == 0) ? 0.180336880111120f : 1.0f;   // 0.125*log2(e)
        const int h = hpair + wn;
        const int sb = (m0 & 1023) + wm * 64;
#pragma unroll
        for (int mt = 0; mt < 4; ++mt)
#pragma unroll
            for (int r = 0; r < 4; ++r) {
                int s = sb + mt * 16 + quad * 4 + r;
                size_t rowo = ((size_t)(b * HH + h) * SS + s) * DH;
#pragma unroll
                for (int nt = 0; nt < 4; ++nt)
                    O[rowo + nt * 16 + ln] = f2b((acc[mt][nt][r] + bias[nt]) * sc);
            }
    } else {
        __syncthreads();
#pragma unroll
        for (int mt = 0; mt < 4; ++mt)
#pragma unroll
            for (int nt = 0; nt < 4; ++nt)
#pragma unroll
                for (int r = 0; r < 4; ++r)
                    lds[(wn * 64 + nt * 16 + ln) * 136 + wm * 64 + mt * 16 + quad * 4 + r] =
                        f2b(acc[mt][nt][r] + bias[nt]);
        __syncthreads();
        const int cc = u >> 1, half = u & 1;
        const int h = hpair + (cc >> 6), e = cc & 63;
        const int sb = (m0 & 1023) + half * 64;
        unsigned short* dst = Vtb + ((size_t)(b * HH + h) * DH + e) * SS + sb;
        const unsigned short* srcp = lds + cc * 136 + half * 64;
#pragma unroll
        for (int i = 0; i < 8; ++i)
            *(uint4*)(dst + i * 8) = *(const uint4*)(srcp + i * 8);
    }
}

// ---------------------------------------------------------------------------
// Kernel 2: flash attention, 32x32x16 MFMA core, in-register P (exact R6
// version, measured 73.7us at 4 blocks/CU). R9 lesson: launch_bounds(256,5)
// capped the UNIFIED VGPR+AGPR file to ~102/wave -> VGPR 48 + f32x16 acc
// spill to scratch (FETCH+WRITE 350MB, 2.4x slower). (256,4) is the max
// occupancy hint this register footprint tolerates.
// grid (8, 192).
// ---------------------------------------------------------------------------
__global__ __launch_bounds__(256, 4) void attn_kernel(
    const unsigned short* __restrict__ Kb,
    const unsigned short* __restrict__ Vtb,
    unsigned short* __restrict__ Qb)
{
    __shared__ __align__(16) unsigned short Ks[2][4096];   // dbuf [64 t][64 e] swz; also Q stage / O^T epilogue
    __shared__ __align__(16) unsigned short Vs[2][4096];   // dbuf [64 e][64 t] swz
    unsigned short* KsF = &Ks[0][0];                       // 16 KB flat view

    const int u = threadIdx.x;
    // XCD swizzle (bijective: 1536 % 8 == 0): flat -> (head, qtile)
    const int flat = (blockIdx.y << 3) | blockIdx.x;       // 0..1535, xcd = flat&7
    const int swz  = (flat & 7) * 192 + (flat >> 3);
    const int s0 = (swz & 7) << 7;
    const int bh = swz >> 3;

    const int lane = u & 63, w = u >> 6;
    const int l31 = lane & 31, hi = lane >> 5;
    const int r7 = l31 & 7;

    unsigned short* Qg = Qb + ((size_t)bh * SS + s0) * DH;
    const unsigned short* Kg = Kb + (size_t)bh * SS * DH;
    const unsigned short* Vg = Vtb + (size_t)bh * DH * SS;

    const int srow = lane >> 3;
    const int cg8  = ((lane & 7) ^ srow) * 8;

    // staging pointers (K rows t, V rows e; 16B/lane async16)
    const unsigned short* kp0 = Kg + (size_t)((w * 2 + 0) * 8 + srow) * DH + cg8;
    const unsigned short* kp1 = Kg + (size_t)((w * 2 + 1) * 8 + srow) * DH + cg8;
    const unsigned short* vp0 = Vg + (size_t)((w * 2 + 0) * 8 + srow) * SS + cg8;
    const unsigned short* vp1 = Vg + (size_t)((w * 2 + 1) * 8 + srow) * SS + cg8;

    // ---- stage Q (16 KB) through the Ks region, consume into regs ----
#pragma unroll
    for (int j = 0; j < 4; ++j) {
        const int r0 = (w * 4 + j) * 8 + srow;
        async16(Qg + (size_t)r0 * DH + cg8, KsF + (w * 4 + j) * 512);
    }
    __syncthreads();   // Q resident (implicit vmcnt(0))

    // Q B-fragments: lane holds Q[m = w*32 + l31][e = ke*16 + hi*8 + j]
    short8 qf[4];
    {
        const unsigned short* qrow = KsF + (w * 32 + l31) * 64;
#pragma unroll
        for (int ke = 0; ke < 4; ++ke)
            qf[ke] = *(const short8*)(qrow + (((ke * 2 + hi) ^ r7) * 8));
    }
    __syncthreads();   // ALL waves consumed Q -> Ks region recyclable

    // ---- stage K/V tile 0 into buffer 0 ----
    async16(kp0, &Ks[0][(w * 2 + 0) * 512]);
    async16(kp1, &Ks[0][(w * 2 + 1) * 512]);
    async16(vp0, &Vs[0][(w * 2 + 0) * 512]);
    async16(vp1, &Vs[0][(w * 2 + 1) * 512]);
    kp0 += 64 * DH; kp1 += 64 * DH; vp0 += 64; vp1 += 64;
    __syncthreads();   // tile0 resident

    short8 ones;
#pragma unroll
    for (int i = 0; i < 8; ++i) ones[i] = (short)0x3F80;   // bf16 1.0

    // A-fragment LDS offsets (shared by K and V tiles): row l31 (+tt*32 via +2048)
    int off[4];
#pragma unroll
    for (int x = 0; x < 4; ++x) off[x] = l31 * 64 + (((x * 2 + hi) ^ r7) * 8);

    f32x16 oA, oB, oL;
#pragma unroll
    for (int i = 0; i < 16; ++i) { oA[i] = 0.f; oB[i] = 0.f; oL[i] = 0.f; }

    for (int kt = 0; kt < 16; ++kt) {
        const int cur = kt & 1;
        // prefetch next K/V tile into the other buffer (end-of-iter barrier drains)
        if (kt < 15) {
            unsigned short* lk = &Ks[cur ^ 1][(w * 2) * 512];
            unsigned short* lv = &Vs[cur ^ 1][(w * 2) * 512];
            async16(kp0, lk);
            async16(kp1, lk + 512);
            async16(vp0, lv);
            async16(vp1, lv + 512);
            kp0 += 64 * DH; kp1 += 64 * DH; vp0 += 64; vp1 += 64;
        }
        const unsigned short* kc = Ks[cur];
        const unsigned short* vc = Vs[cur];

        // --- QK^T (swapped): sA = S^T rows t 0..31, sB = t 32..63, cols m ---
        f32x16 sA, sB;
#pragma unroll
        for (int i = 0; i < 16; ++i) { sA[i] = 0.f; sB[i] = 0.f; }
        __builtin_amdgcn_s_setprio(1);
#pragma unroll
        for (int ke = 0; ke < 4; ++ke) {
            short8 kf0 = *(const short8*)(kc + off[ke]);
            short8 kf1 = *(const short8*)(kc + off[ke] + 2048);
            sA = __builtin_amdgcn_mfma_f32_32x32x16_bf16(kf0, qf[ke], sA, 0, 0, 0);
            sB = __builtin_amdgcn_mfma_f32_32x32x16_bf16(kf1, qf[ke], sB, 0, 0, 0);
        }
        __builtin_amdgcn_s_setprio(0);

        // --- exp2 + pack to bf16 words (row-sum via oL MFMA below) ---
        // W[tt][i] covers t = tt*32 + {0,2,8,10,16,18,24,26}[i] + 4*hi + {0,1}
        unsigned int W0[8], W1[8];
#pragma unroll
        for (int i = 0; i < 8; ++i) {
            W0[i] = pk2(fast_exp2(sA[2 * i]), fast_exp2(sA[2 * i + 1]));
            W1[i] = pk2(fast_exp2(sB[2 * i]), fast_exp2(sB[2 * i + 1]));
        }

        // --- permlane32_swap -> PV B-frags; PV + row-sum MFMAs ---
        // permlane32_swap semantics (CDNA4): new_vdst[32:63] = old_src0[0:31],
        // new_src0[0:31] = old_vdst[32:63]; swap(W[0],W[2]) -> (.x = frag word
        // 0, .y = frag word 2) on BOTH halves.
        __builtin_amdgcn_s_setprio(1);
#define PV_STEP(Wt, ks) {                                                              \
        union { unsigned int wv[4]; short8 s; } pu;                                    \
        { uv2 rr = __builtin_amdgcn_permlane32_swap(Wt[4 * ((ks) & 1) + 0],            \
                                                    Wt[4 * ((ks) & 1) + 2], false, false); \
          pu.wv[0] = rr.x; pu.wv[2] = rr.y; }                                          \
        { uv2 rr = __builtin_amdgcn_permlane32_swap(Wt[4 * ((ks) & 1) + 1],            \
                                                    Wt[4 * ((ks) & 1) + 3], false, false); \
          pu.wv[1] = rr.x; pu.wv[3] = rr.y; }                                          \
        oL = __builtin_amdgcn_mfma_f32_32x32x16_bf16(ones, pu.s, oL, 0, 0, 0);         \
        short8 vf0 = *(const short8*)(vc + off[(ks)]);                                 \
        short8 vf1 = *(const short8*)(vc + off[(ks)] + 2048);                          \
        oA = __builtin_amdgcn_mfma_f32_32x32x16_bf16(vf0, pu.s, oA, 0, 0, 0);          \
        oB = __builtin_amdgcn_mfma_f32_32x32x16_bf16(vf1, pu.s, oB, 0, 0, 0); }
        PV_STEP(W0, 0)
        PV_STEP(W0, 1)
        PV_STEP(W1, 2)
        PV_STEP(W1, 3)
#undef PV_STEP
        __builtin_amdgcn_s_setprio(0);

        __syncthreads();   // drains prefetch (vmcnt 0) + guards buffer swap
    }

    // --- epilogue: normalize, transpose O^T -> O via Ks region, store ---
    // oL: every row of D holds sum_t P[m][t] for col m = l31 (A = all-ones).
    const float linv = 1.f / oL[0];

    unsigned short* Ob = KsF + w * 2048;   // wave-private 4KB: [32 m][64 e] swz
#define OSTORE(oc, et) {                                                   \
        _Pragma("unroll")                                                  \
        for (int rg = 0; rg < 4; ++rg) {                                   \
            uv2 wv;                                                        \
            wv.x = pk2(oc[rg * 4 + 0] * linv, oc[rg * 4 + 1] * linv);      \
            wv.y = pk2(oc[rg * 4 + 2] * linv, oc[rg * 4 + 3] * linv);      \
            *(uv2*)(Ob + l31 * 64 + ((((et) * 4 + rg) ^ r7) * 8) + hi * 4) = wv; \
        } }
    OSTORE(oA, 0)
    OSTORE(oB, 1)
#undef OSTORE

    const int rr2 = lane >> 1, q16 = lane & 1, rs = rr2 & 7;
    const unsigned short* orow = KsF + w * 2048 + rr2 * 64;
    unsigned short* gout = Qg + (size_t)(w * 32 + rr2) * DH;
#pragma unroll
    for (int i = 0; i < 4; ++i) {
        const int g = q16 * 4 + i;
        *(uint4*)(gout + g * 8) = *(const uint4*)(orow + ((g ^ rs) * 8));
    }
}

// ---------------------------------------------------------------------------
// Kernel 3: output projection, 128x128 tiles, swizzled. Single-buffer 32KB
// LDS (dbuf measured -15us here: occupancy halving outweighed the pipeline)
// + bijective XCD swizzle (768 = 8*96). out fp32. grid (6, 128).
// ---------------------------------------------------------------------------
__global__ __launch_bounds__(256) void oproj_gemm(
    const unsigned short* __restrict__ Ob,
    const unsigned short* __restrict__ Wot,
    const float* __restrict__ bo32,
    float* __restrict__ out)
{
    __shared__ __align__(16) unsigned short lds[128 * 128];
    unsigned short* As = lds;
    unsigned short* Bs = lds + 128 * 64;

    const int u = threadIdx.x;
    const int lane = u & 63, w = u >> 6;
    const int ln = lane & 15, quad = lane >> 4;
    const int wm = w & 1, wn = w >> 1;

    // XCD swizzle (bijective: 768 = 8*96)
    const int flat = blockIdx.y * 6 + blockIdx.x;
    const int sf   = (flat & 7) * 96 + (flat >> 3);
    const int n0   = (sf % 6) << 7;
    const int m0   = (sf / 6) << 7;
    const int b = m0 >> 10, s0t = m0 & 1023;

    const int rA = w * 32 + (lane >> 3);
    const int c8 = (((lane & 7) ^ (lane >> 3)) * 8);

    f32x4 acc[4][4];
#pragma unroll
    for (int i = 0; i < 4; ++i)
#pragma unroll
        for (int j = 0; j < 4; ++j) acc[i][j] = (f32x4){0.f, 0.f, 0.f, 0.f};

    const unsigned short* Bg = Wot + (size_t)(n0 + rA) * DD + c8;
    unsigned short* lA0 = As + w * 2048;
    unsigned short* lB0 = Bs + w * 2048;

    for (int kb = 0; kb < 12; ++kb) {
        if (kb) __syncthreads();
        const unsigned short* Ag = Ob + ((size_t)(b * HH + kb) * SS + s0t + rA) * DH + c8;
#pragma unroll
        for (int j = 0; j < 4; ++j) {
            async16(Ag + (size_t)j * 8 * DH, lA0 + j * 512);
            async16(Bg + (size_t)j * 8 * DD + kb * 64, lB0 + j * 512);
        }
        __syncthreads();
#pragma unroll
        for (int kh = 0; kh < 2; ++kh) {
            const int sx = ((kh * 4 + quad) ^ (ln & 7)) * 8;
            short8 af[4], bf[4];
#pragma unroll
            for (int t = 0; t < 4; ++t) {
                af[t] = *(const short8*)(As + (wm * 64 + t * 16 + ln) * 64 + sx);
                bf[t] = *(const short8*)(Bs + (wn * 64 + t * 16 + ln) * 64 + sx);
            }
#pragma unroll
            for (int mt = 0; mt < 4; ++mt)
#pragma unroll
                for (int nt = 0; nt < 4; ++nt)
                    acc[mt][nt] = __builtin_amdgcn_mfma_f32_16x16x32_bf16(af[mt], bf[nt], acc[mt][nt], 0, 0, 0);
        }
    }

    float bias[4];
#pragma unroll
    for (int nt = 0; nt < 4; ++nt) bias[nt] = bo32[n0 + wn * 64 + nt * 16 + ln];
#pragma unroll
    for (int mt = 0; mt < 4; ++mt)
#pragma unroll
        for (int r = 0; r < 4; ++r) {
            int m = m0 + wm * 64 + mt * 16 + quad * 4 + r;
            float* orow = out + (size_t)m * DD + n0 + wn * 64;
#pragma unroll
            for (int nt = 0; nt < 4; ++nt)
                orow[nt * 16 + ln] = acc[mt][nt][r] + bias[nt];
        }
}

extern "C" void kernel_launch(void* const* d_in, const int* in_sizes, int n_in,
                              void* d_out, int out_size, void* d_ws, size_t ws_size,
                              hipStream_t stream)
{
    const void* X  = d_in[0];
    const void* Wq = d_in[1];
    const void* bq = d_in[2];
    const void* Wk = d_in[3];
    const void* bk = d_in[4];
    const void* Wv = d_in[5];
    const void* bv = d_in[6];
    const void* Wo = d_in[7];
    const void* bo = d_in[8];
    float* out = (float*)d_out;

    const size_t NE = (size_t)BB * HH * SS * DH;   // 12,582,912
    char* p = (char*)d_ws;
    int* flag = (int*)p;                 p += 256;
    unsigned short* Qb  = (unsigned short*)p;  p += NE * 2;
    unsigned short* Kb  = (unsigned short*)p;  p += NE * 2;
    unsigned short* Vtb = (unsigned short*)p;  p += NE * 2;
    unsigned short* Xb  = (unsigned short*)p;  p += (size_t)BB * SS * DD * 2;
    unsigned short* Wc  = (unsigned short*)p;  p += (size_t)3 * DD * DD * 2;
    unsigned short* Wot = (unsigned short*)p;  p += (size_t)DD * DD * 2;
    unsigned short* bcb = (unsigned short*)p;  p += 4608;
    float* bo32 = (float*)p;                   p += 3072;

    detect_kernel<<<1, 256, 0, stream>>>((const unsigned short*)X, flag);
    prep_all<<<6721, 256, 0, stream>>>(X, Wq, bq, Wk, bk, Wv, bv, Wo, bo, flag,
                                       Xb, Wc, Wot, bcb, bo32);
    qkv_gemm<<<dim3(18, 128), 256, 0, stream>>>(Xb, Wc, bcb, Qb, Kb, Vtb);
    attn_kernel<<<dim3(8, 192), 256, 0, stream>>>(Kb, Vtb, Qb);
    oproj_gemm<<<dim3(6, 128), 256, 0, stream>>>(Qb, Wot, bo32, out);
}